// Round 4
// baseline (188.654 us; speedup 1.0000x reference)
//
#include <hip/hip_runtime.h>
#include <hip/hip_bf16.h>

#define CCH 256      // channels
#define HH 128
#define WW 128
#define SS (HH*WW)   // 16384 pixels per batch
#define NB 8         // batch
#define NK 19        // keypoints
#define STILE 32     // pixels per tile
#define TPB 8        // tiles per block (persistent)
#define NTILES (NB * (SS / STILE))   // 4096
#define NBLK (NTILES / TPB)          // 512

typedef __attribute__((ext_vector_type(8))) short short8v;   // 8 bf16 = 4 VGPR (MFMA operand)
typedef __attribute__((ext_vector_type(4))) float f32x4;     // MFMA accum

static __device__ __forceinline__ unsigned short f2bf(float x) {
    __hip_bfloat16 h = __float2bfloat16(x);
    return *reinterpret_cast<unsigned short*>(&h);
}
static __device__ __forceinline__ float bf2f(unsigned short u) {
    union { unsigned int i; float f; } z; z.i = ((unsigned int)u) << 16; return z.f;
}
static __device__ __forceinline__ float tanh_fast(float x) {
    float e = __expf(2.f * x);
    return 1.f - 2.f / (e + 1.f);
}

// ---------------------------------------------------------------------------
// Kernel 1: precompute folded biases, delta weights, keypoint pixels, and
// img_fc_w rearranged to bf16 in MFMA A-fragment order:
//   Wfrag[((ks*16 + ot)*64 + lane)*8 + j] = bf16(W[ot*16 + (lane&15)][ks*32 + (lane>>4)*8 + j])
// ---------------------------------------------------------------------------
__global__ __launch_bounds__(256) void precompute_kernel(
    const float* __restrict__ kf,        // [B,K,3]
    const float* __restrict__ img_fc_w,  // [256,256]
    const float* __restrict__ img_fc_b,  // [256]
    const float* __restrict__ kp_proj_w, // [19,19]
    const float* __restrict__ kp_proj_b, // [19]
    const float* __restrict__ kp_fc_w,   // [256,19]
    const float* __restrict__ kp_fc_b,   // [256]
    float* __restrict__ cb,              // [256] combined bias
    float* __restrict__ delta,           // [256*19]
    int* __restrict__ pix,               // [B*K]
    unsigned short* __restrict__ Wfrag)  // [8*16*64*8]
{
    int t = threadIdx.x;
    {
        float acc = img_fc_b[t] + kp_fc_b[t];
        for (int k2 = 0; k2 < NK; ++k2) acc += kp_fc_w[t * NK + k2] * kp_proj_b[k2];
        cb[t] = acc;
        for (int k = 0; k < NK; ++k) {
            float d = 0.f;
            for (int k2 = 0; k2 < NK; ++k2) d += kp_fc_w[t * NK + k2] * kp_proj_w[k2 * NK + k];
            delta[t * NK + k] = d;
        }
    }
    if (t < NB * NK) {
        float kx = kf[t * 3 + 0], ky = kf[t * 3 + 1], vis = kf[t * 3 + 2];
        int p = -1;
        if (vis > 0.f) {
            int xi = (int)fminf(fmaxf(kx * (1.f / (float)WW), 0.f), (float)(WW - 1));
            int yi = (int)fminf(fmaxf(ky * (1.f / (float)HH), 0.f), (float)(HH - 1));
            p = yi * WW + xi;
        }
        pix[t] = p;
    }
    for (int g = t; g < 8 * 16 * 64; g += 256) {
        int lane = g & 63;
        int ot = (g >> 6) & 15;
        int ks = g >> 10;
        int o = ot * 16 + (lane & 15);
        int c0 = ks * 32 + (lane >> 4) * 8;
#pragma unroll
        for (int j = 0; j < 8; ++j)
            Wfrag[g * 8 + j] = f2bf(img_fc_w[o * CCH + c0 + j]);
    }
}

// ---------------------------------------------------------------------------
// Kernel 2: persistent pipelined GEMM+epilogue. 512 blocks x 512 thr (8 waves).
// Each block: 8 consecutive tiles of 32 px. Double-buffered bf16 X in LDS.
// Per iter: issue next-tile loads (regs) -> barrier -> K-loop (pure LDS+MFMA,
// A-frags persistent in VGPRs) -> reduce -> store -> cvt+ds_write next buffer.
// ---------------------------------------------------------------------------
__global__ __launch_bounds__(512, 4) void main_kernel(
    const float* __restrict__ img,        // [B,256,16384]
    const unsigned short* __restrict__ Wfrag,
    const float* __restrict__ cb,         // [256]
    const float* __restrict__ aw,         // attn_fc_w [256]
    const float* __restrict__ attn_b,     // [1]
    float* __restrict__ out)              // [B,256,16384]
{
    __shared__ unsigned short Xl[2][STILE * 256];  // 2 x 16KB bf16 [s][c] swizzled
    __shared__ float partial[8][STILE];
    __shared__ float cbl[256];
    __shared__ float awl[256];

    const int t = threadIdx.x;
    const int l = t & 63;        // lane
    const int w = t >> 6;        // wave 0..7
    const int sl = t & 31;       // staging/store pixel this thread owns
    const int cg = t >> 5;       // 0..15: channel group (16 ch)
    const int c0 = cg * 16;

    // ---- persistent A fragments: this wave's 2 o-rows, all 8 K-steps ------
    short8v a[2][8];
#pragma unroll
    for (int ks = 0; ks < 8; ++ks)
#pragma unroll
        for (int m = 0; m < 2; ++m)
            a[m][ks] = *reinterpret_cast<const short8v*>(
                &Wfrag[(((ks * 16 + (w * 2 + m)) * 64) + l) * 8]);

    if (t < 256) { cbl[t] = cb[t]; awl[t] = aw[t]; }
    const float attnb = attn_b[0];

    const int tile0 = blockIdx.x * TPB;

    // ---- prologue: load + stage tile0 into Xl[0] --------------------------
    float xf[16];
    {
        int tile = tile0;
        const float* imgb = img + (size_t)(tile >> 9) * CCH * SS + (tile & 511) * STILE;
#pragma unroll
        for (int j = 0; j < 16; ++j)
            xf[j] = imgb[(size_t)(c0 + j) * SS + sl];
#pragma unroll
        for (int jb = 0; jb < 2; ++jb) {
            short8v pk;
#pragma unroll
            for (int e = 0; e < 8; ++e) pk[e] = (short)f2bf(xf[jb * 8 + e]);
            int cblk = cg * 2 + jb;
            Xl[0][0] = Xl[0][0];  // no-op
            *reinterpret_cast<short8v*>(
                &Xl[0][sl * 256 + ((cblk ^ (sl & 7)) << 3)]) = pk;
        }
    }

    int cur = 0;
    for (int it = 0; it < TPB; ++it) {
        const int tile = tile0 + it;
        const int b = tile >> 9;
        const int sb = (tile & 511) * STILE;

        // -- issue next tile's loads (in flight across barrier + compute) ---
        if (it + 1 < TPB) {
            const int tn = tile + 1;
            const float* imgn = img + (size_t)(tn >> 9) * CCH * SS + (tn & 511) * STILE;
#pragma unroll
            for (int j = 0; j < 16; ++j)
                xf[j] = imgn[(size_t)(c0 + j) * SS + sl];
        }

        __syncthreads();   // Xl[cur] staged (ds_writes of previous iter/prologue)

        // -- K loop: pure LDS + MFMA ----------------------------------------
        const unsigned short* Xc = &Xl[cur][0];
        f32x4 acc[2][2];
#pragma unroll
        for (int m = 0; m < 2; ++m)
#pragma unroll
            for (int n = 0; n < 2; ++n)
                acc[m][n] = (f32x4){0.f, 0.f, 0.f, 0.f};

#pragma unroll
        for (int ks = 0; ks < 8; ++ks) {
            const int cblk = ks * 4 + (l >> 4);
            const int s0 = (l & 15);
            const int s1 = 16 + s0;
            short8v bf0 = *reinterpret_cast<const short8v*>(
                &Xc[s0 * 256 + ((cblk ^ (s0 & 7)) << 3)]);
            short8v bf1 = *reinterpret_cast<const short8v*>(
                &Xc[s1 * 256 + ((cblk ^ (s1 & 7)) << 3)]);
            acc[0][0] = __builtin_amdgcn_mfma_f32_16x16x32_bf16(a[0][ks], bf0, acc[0][0], 0, 0, 0);
            acc[1][0] = __builtin_amdgcn_mfma_f32_16x16x32_bf16(a[1][ks], bf0, acc[1][0], 0, 0, 0);
            acc[0][1] = __builtin_amdgcn_mfma_f32_16x16x32_bf16(a[0][ks], bf1, acc[0][1], 0, 0, 0);
            acc[1][1] = __builtin_amdgcn_mfma_f32_16x16x32_bf16(a[1][ks], bf1, acc[1][1], 0, 0, 0);
        }

        // -- epilogue: wave partial of sum_o aw[o]*tanh(T[o,s]+cb[o]) -------
        // D layout: s = n*16 + (l&15), o = (w*2+m)*16 + (l>>4)*4 + r
        float p2[2];
#pragma unroll
        for (int n = 0; n < 2; ++n) {
            float accp = 0.f;
#pragma unroll
            for (int m = 0; m < 2; ++m)
#pragma unroll
                for (int r = 0; r < 4; ++r) {
                    int o = (w * 2 + m) * 16 + ((l >> 4) << 2) + r;
                    accp += awl[o] * tanh_fast(acc[m][n][r] + cbl[o]);
                }
            accp += __shfl_xor(accp, 16);
            accp += __shfl_xor(accp, 32);
            p2[n] = accp;
        }
        if (l < 16) {
            partial[w][l] = p2[0];
            partial[w][16 + l] = p2[1];
        }
        __syncthreads();

        // -- per-thread score + store its 16 channels of pixel sl -----------
        float z = attnb;
#pragma unroll
        for (int ww = 0; ww < 8; ++ww) z += partial[ww][sl];
        float sc = 1.f / (1.f + __expf(-z));

#pragma unroll
        for (int jb = 0; jb < 2; ++jb) {
            int cblk = cg * 2 + jb;
            short8v v = *reinterpret_cast<const short8v*>(
                &Xc[sl * 256 + ((cblk ^ (sl & 7)) << 3)]);
#pragma unroll
            for (int e = 0; e < 8; ++e)
                out[(size_t)(b * CCH + c0 + jb * 8 + e) * SS + sb + sl] =
                    bf2f((unsigned short)v[e]) * sc;
        }

        // -- cvt + stage next tile into the other buffer --------------------
        if (it + 1 < TPB) {
            unsigned short* Xn = &Xl[cur ^ 1][0];
#pragma unroll
            for (int jb = 0; jb < 2; ++jb) {
                short8v pk;
#pragma unroll
                for (int e = 0; e < 8; ++e) pk[e] = (short)f2bf(xf[jb * 8 + e]);
                int cblk = cg * 2 + jb;
                *reinterpret_cast<short8v*>(
                    &Xn[sl * 256 + ((cblk ^ (sl & 7)) << 3)]) = pk;
            }
        }
        cur ^= 1;
    }
}

// ---------------------------------------------------------------------------
// Kernel 3: exact fp32 fixup for keypoint pixels (<=152). One block per (b,k).
// ---------------------------------------------------------------------------
__global__ __launch_bounds__(256) void fixup_kernel(
    const float* __restrict__ img,
    const float* __restrict__ img_fc_w,
    const float* __restrict__ aw,
    const float* __restrict__ attn_b,
    const float* __restrict__ cb,
    const float* __restrict__ delta,
    const int* __restrict__ pix,
    float* __restrict__ out)
{
    int bk = blockIdx.x;            // 0..151
    int b = bk / NK;
    int p = pix[bk];
    if (p < 0) return;              // uniform branch, before any barrier
    __shared__ float x[256];
    __shared__ float red[256];
    __shared__ float ssc;
    int t = threadIdx.x;
    const float* imgb = img + (size_t)b * CCH * SS;
    x[t] = imgb[(size_t)t * SS + p];
    __syncthreads();
    float dsum = 0.f;
    for (int k2 = 0; k2 < NK; ++k2)
        if (pix[b * NK + k2] == p) dsum += delta[t * NK + k2];
    float acc = cb[t] + dsum;
    for (int c = 0; c < CCH; ++c) acc += img_fc_w[t * CCH + c] * x[c];
    red[t] = aw[t] * tanh_fast(acc);
    __syncthreads();
    for (int off = 128; off > 0; off >>= 1) {
        if (t < off) red[t] += red[t + off];
        __syncthreads();
    }
    if (t == 0) ssc = 1.f / (1.f + __expf(-(red[0] + attn_b[0])));
    __syncthreads();
    out[(size_t)(b * CCH + t) * SS + p] = x[t] * ssc;
}

// ---------------------------------------------------------------------------
extern "C" void kernel_launch(void* const* d_in, const int* in_sizes, int n_in,
                              void* d_out, int out_size, void* d_ws, size_t ws_size,
                              hipStream_t stream) {
    (void)in_sizes; (void)n_in; (void)out_size; (void)ws_size;
    const float* img       = (const float*)d_in[0];
    const float* kf        = (const float*)d_in[1];
    const float* img_fc_w  = (const float*)d_in[2];
    const float* img_fc_b  = (const float*)d_in[3];
    const float* kp_proj_w = (const float*)d_in[4];
    const float* kp_proj_b = (const float*)d_in[5];
    const float* kp_fc_w   = (const float*)d_in[6];
    const float* kp_fc_b   = (const float*)d_in[7];
    const float* attn_fc_w = (const float*)d_in[8];
    const float* attn_fc_b = (const float*)d_in[9];
    float* out = (float*)d_out;

    char* ws = (char*)d_ws;
    float* cb             = (float*)(ws);            // 256 f  ->   1024 B
    float* delta          = (float*)(ws + 1024);     // 4864 f -> 19456 B
    int*   pix            = (int*)  (ws + 20480);    // 152 i  ->   608 B
    unsigned short* Wfrag = (unsigned short*)(ws + 21504); // 65536 u16 -> 131072 B

    precompute_kernel<<<1, 256, 0, stream>>>(kf, img_fc_w, img_fc_b, kp_proj_w,
                                             kp_proj_b, kp_fc_w, kp_fc_b,
                                             cb, delta, pix, Wfrag);
    main_kernel<<<NBLK, 512, 0, stream>>>(img, Wfrag, cb,
                                          attn_fc_w, attn_fc_b, out);
    fixup_kernel<<<NB * NK, 256, 0, stream>>>(img, img_fc_w, attn_fc_w, attn_fc_b,
                                              cb, delta, pix, out);
}

// Round 5
// 104.137 us; speedup vs baseline: 1.8116x; 1.8116x over previous
//
#include <hip/hip_runtime.h>
#include <hip/hip_bf16.h>

#define CCH 256      // channels
#define HH 128
#define WW 128
#define SS (HH*WW)   // 16384 pixels per batch
#define NB 8         // batch
#define NK 19        // keypoints
#define STILE 64     // pixels per block

typedef __attribute__((ext_vector_type(8))) short short8v;   // 8 bf16 = 4 VGPR (MFMA operand)
typedef __attribute__((ext_vector_type(4))) float f32x4;     // MFMA accum

static __device__ __forceinline__ unsigned short f2bf(float x) {
    __hip_bfloat16 h = __float2bfloat16(x);
    return *reinterpret_cast<unsigned short*>(&h);
}
static __device__ __forceinline__ float tanh_fast(float x) {
    // 1 - 2/(e^{2x}+1): monotone, no inf-inf, exact +/-1 saturation
    float e = __expf(2.f * x);
    return 1.f - 2.f / (e + 1.f);
}

// ---------------------------------------------------------------------------
// Kernel 1: precompute folded biases, delta weights, keypoint pixels, and
// img_fc_w rearranged to bf16 in MFMA A-fragment order:
//   Wfrag[((ks*16 + ot)*64 + lane)*8 + j] = bf16(W[ot*16 + (lane&15)][ks*32 + (lane>>4)*8 + j])
// ---------------------------------------------------------------------------
__global__ __launch_bounds__(256) void precompute_kernel(
    const float* __restrict__ kf,        // [B,K,3]
    const float* __restrict__ img_fc_w,  // [256,256]
    const float* __restrict__ img_fc_b,  // [256]
    const float* __restrict__ kp_proj_w, // [19,19]
    const float* __restrict__ kp_proj_b, // [19]
    const float* __restrict__ kp_fc_w,   // [256,19]
    const float* __restrict__ kp_fc_b,   // [256]
    float* __restrict__ cb,              // [256] combined bias
    float* __restrict__ delta,           // [256*19]
    int* __restrict__ pix,               // [B*K]
    unsigned short* __restrict__ Wfrag)  // [8*16*64*8]
{
    int t = threadIdx.x;
    {
        float acc = img_fc_b[t] + kp_fc_b[t];
        for (int k2 = 0; k2 < NK; ++k2) acc += kp_fc_w[t * NK + k2] * kp_proj_b[k2];
        cb[t] = acc;
        for (int k = 0; k < NK; ++k) {
            float d = 0.f;
            for (int k2 = 0; k2 < NK; ++k2) d += kp_fc_w[t * NK + k2] * kp_proj_w[k2 * NK + k];
            delta[t * NK + k] = d;
        }
    }
    if (t < NB * NK) {
        float kx = kf[t * 3 + 0], ky = kf[t * 3 + 1], vis = kf[t * 3 + 2];
        int p = -1;
        if (vis > 0.f) {
            int xi = (int)fminf(fmaxf(kx * (1.f / (float)WW), 0.f), (float)(WW - 1));
            int yi = (int)fminf(fmaxf(ky * (1.f / (float)HH), 0.f), (float)(HH - 1));
            p = yi * WW + xi;
        }
        pix[t] = p;
    }
    for (int g = t; g < 8 * 16 * 64; g += 256) {
        int lane = g & 63;
        int ot = (g >> 6) & 15;
        int ks = g >> 10;
        int o = ot * 16 + (lane & 15);
        int c0 = ks * 32 + (lane >> 4) * 8;
#pragma unroll
        for (int j = 0; j < 8; ++j)
            Wfrag[g * 8 + j] = f2bf(img_fc_w[o * CCH + c0 + j]);
    }
}

// ---------------------------------------------------------------------------
// Kernel 2: main fused GEMM + epilogue. Block = 512 thr (8 waves), 2048 blocks.
// Tile: 256 o x 64 s. Wave w owns o in [w*32, w*32+32)  (m = 2 frags).
// Phase 1: scalar per-channel loads -> bf16 -> swizzled [s][c] LDS (1 barrier).
// Phase 2: K-loop (LDS B-frags + L2-hot global A-frags + MFMA).
// Phase 3: tanh/attn reduce -> score[64] in LDS.
// Phase 4: reload tile as float4 (L3-resident, zero HBM cost) * score -> out.
// __launch_bounds__(512,8) caps VGPR at 64 -> 4 blocks/CU (LDS 37KB also ok).
// ---------------------------------------------------------------------------
__global__ __launch_bounds__(512, 8) void main_kernel(
    const float* __restrict__ img,        // [B,256,16384]
    const unsigned short* __restrict__ Wfrag,
    const float* __restrict__ cb,         // [256]
    const float* __restrict__ aw,         // attn_fc_w [256]
    const float* __restrict__ attn_b,     // [1]
    float* __restrict__ out)              // [B,256,16384]
{
    __shared__ unsigned short Xl[64 * 256];   // 32KB bf16 [s][c], 16B-block swizzled
    __shared__ float partial[8][64];
    __shared__ float scl[64];
    __shared__ float cbl[256];
    __shared__ float awl[256];

    const int t = threadIdx.x;
    const int l = t & 63;        // lane
    const int w = t >> 6;        // wave 0..7
    const int bid = blockIdx.x;
    const int b = bid >> 8;
    const int sb = (bid & 255) * STILE;
    const float* imgb = img + (size_t)b * CCH * SS;

    if (t < 256) { cbl[t] = cb[t]; awl[t] = aw[t]; }

    const int sl = t & 63;            // pixel-in-tile this thread owns (staging)
    const int c0 = (t >> 6) * 32;     // 32 channels this thread owns (staging)

    // ---- phase 1: 32 independent scalar loads -> bf16 -> swizzled LDS -----
    {
        float xf[32];
#pragma unroll
        for (int j = 0; j < 32; ++j)
            xf[j] = imgb[(size_t)(c0 + j) * SS + sb + sl];
#pragma unroll
        for (int jb = 0; jb < 4; ++jb) {
            short8v pk;
#pragma unroll
            for (int e = 0; e < 8; ++e) pk[e] = (short)f2bf(xf[jb * 8 + e]);
            int cblk = (c0 >> 3) + jb;
            int idx = sl * 256 + ((cblk ^ (sl & 7)) << 3);
            *reinterpret_cast<short8v*>(&Xl[idx]) = pk;
        }
    }
    __syncthreads();

    // ---- phase 2: K loop, 8 steps of K=32, 8 MFMA per step per wave -------
    f32x4 acc[2][4];
#pragma unroll
    for (int m = 0; m < 2; ++m)
#pragma unroll
        for (int n = 0; n < 4; ++n)
            acc[m][n] = (f32x4){0.f, 0.f, 0.f, 0.f};

#pragma unroll
    for (int ks = 0; ks < 8; ++ks) {
        short8v a[2], bf[4];
#pragma unroll
        for (int m = 0; m < 2; ++m) {
            int ot = w * 2 + m;
            a[m] = *reinterpret_cast<const short8v*>(
                &Wfrag[(((ks * 16 + ot) * 64) + l) * 8]);
        }
#pragma unroll
        for (int n = 0; n < 4; ++n) {
            int s = n * 16 + (l & 15);
            int cblk = ks * 4 + (l >> 4);
            int idx = s * 256 + ((cblk ^ (s & 7)) << 3);
            bf[n] = *reinterpret_cast<const short8v*>(&Xl[idx]);
        }
#pragma unroll
        for (int m = 0; m < 2; ++m)
#pragma unroll
            for (int n = 0; n < 4; ++n)
                acc[m][n] = __builtin_amdgcn_mfma_f32_16x16x32_bf16(a[m], bf[n], acc[m][n], 0, 0, 0);
    }

    // ---- phase 3: score[s] = sigmoid(attn_b + sum_o aw[o]*tanh(T[o,s]+cb[o]))
    // D layout: col(=s within frag) = l&15, row(=o within frag) = (l>>4)*4 + r
    float p4[4];
#pragma unroll
    for (int n = 0; n < 4; ++n) {
        float accp = 0.f;
#pragma unroll
        for (int m = 0; m < 2; ++m)
#pragma unroll
            for (int r = 0; r < 4; ++r) {
                int o = (w * 2 + m) * 16 + ((l >> 4) << 2) + r;
                accp += awl[o] * tanh_fast(acc[m][n][r] + cbl[o]);
            }
        accp += __shfl_xor(accp, 16);
        accp += __shfl_xor(accp, 32);
        p4[n] = accp;
    }
    if (l < 16) {
#pragma unroll
        for (int n = 0; n < 4; ++n) partial[w][n * 16 + l] = p4[n];
    }
    __syncthreads();
    if (t < 64) {
        float z = attn_b[0];
#pragma unroll
        for (int ww = 0; ww < 8; ++ww) z += partial[ww][t];
        scl[t] = 1.f / (1.f + __expf(-z));
    }
    __syncthreads();

    // ---- phase 4: reload tile as float4 (L3-hot), scale, store ------------
    // idx = t + it*512: c = idx>>4 (0..255), q = (idx&15)*4 (px within tile).
    // Per inst: 4 rows x 256B contiguous. scl read is broadcast/2-way (free).
#pragma unroll
    for (int it = 0; it < 8; ++it) {
        int idx = t + it * 512;
        int c = idx >> 4;
        int q = (idx & 15) * 4;
        float4 v = *reinterpret_cast<const float4*>(imgb + (size_t)c * SS + sb + q);
        float4 s4 = *reinterpret_cast<const float4*>(&scl[q]);
        float4 o4;
        o4.x = v.x * s4.x;
        o4.y = v.y * s4.y;
        o4.z = v.z * s4.z;
        o4.w = v.w * s4.w;
        *reinterpret_cast<float4*>(out + (size_t)(b * CCH + c) * SS + sb + q) = o4;
    }
}

// ---------------------------------------------------------------------------
// Kernel 3: exact fp32 fixup for keypoint pixels (<=152). One block per (b,k).
// ---------------------------------------------------------------------------
__global__ __launch_bounds__(256) void fixup_kernel(
    const float* __restrict__ img,
    const float* __restrict__ img_fc_w,
    const float* __restrict__ aw,
    const float* __restrict__ attn_b,
    const float* __restrict__ cb,
    const float* __restrict__ delta,
    const int* __restrict__ pix,
    float* __restrict__ out)
{
    int bk = blockIdx.x;            // 0..151
    int b = bk / NK;
    int p = pix[bk];
    if (p < 0) return;              // uniform branch, before any barrier
    __shared__ float x[256];
    __shared__ float red[256];
    __shared__ float ssc;
    int t = threadIdx.x;
    const float* imgb = img + (size_t)b * CCH * SS;
    x[t] = imgb[(size_t)t * SS + p];
    __syncthreads();
    float dsum = 0.f;
    for (int k2 = 0; k2 < NK; ++k2)
        if (pix[b * NK + k2] == p) dsum += delta[t * NK + k2];
    float acc = cb[t] + dsum;
    for (int c = 0; c < CCH; ++c) acc += img_fc_w[t * CCH + c] * x[c];
    red[t] = aw[t] * tanh_fast(acc);
    __syncthreads();
    for (int off = 128; off > 0; off >>= 1) {
        if (t < off) red[t] += red[t + off];
        __syncthreads();
    }
    if (t == 0) ssc = 1.f / (1.f + __expf(-(red[0] + attn_b[0])));
    __syncthreads();
    out[(size_t)(b * CCH + t) * SS + p] = x[t] * ssc;
}

// ---------------------------------------------------------------------------
extern "C" void kernel_launch(void* const* d_in, const int* in_sizes, int n_in,
                              void* d_out, int out_size, void* d_ws, size_t ws_size,
                              hipStream_t stream) {
    (void)in_sizes; (void)n_in; (void)out_size; (void)ws_size;
    const float* img       = (const float*)d_in[0];
    const float* kf        = (const float*)d_in[1];
    const float* img_fc_w  = (const float*)d_in[2];
    const float* img_fc_b  = (const float*)d_in[3];
    const float* kp_proj_w = (const float*)d_in[4];
    const float* kp_proj_b = (const float*)d_in[5];
    const float* kp_fc_w   = (const float*)d_in[6];
    const float* kp_fc_b   = (const float*)d_in[7];
    const float* attn_fc_w = (const float*)d_in[8];
    const float* attn_fc_b = (const float*)d_in[9];
    float* out = (float*)d_out;

    char* ws = (char*)d_ws;
    float* cb             = (float*)(ws);            // 256 f  ->   1024 B
    float* delta          = (float*)(ws + 1024);     // 4864 f -> 19456 B
    int*   pix            = (int*)  (ws + 20480);    // 152 i  ->   608 B
    unsigned short* Wfrag = (unsigned short*)(ws + 21504); // 65536 u16 -> 131072 B

    precompute_kernel<<<1, 256, 0, stream>>>(kf, img_fc_w, img_fc_b, kp_proj_w,
                                             kp_proj_b, kp_fc_w, kp_fc_b,
                                             cb, delta, pix, Wfrag);
    main_kernel<<<NB * (SS / STILE), 512, 0, stream>>>(img, Wfrag, cb,
                                                       attn_fc_w, attn_fc_b, out);
    fixup_kernel<<<NB * NK, 256, 0, stream>>>(img, img_fc_w, attn_fc_w, attn_fc_b,
                                              cb, delta, pix, out);
}

// Round 6
// 94.690 us; speedup vs baseline: 1.9923x; 1.0998x over previous
//
#include <hip/hip_runtime.h>
#include <hip/hip_bf16.h>

#define CCH 256      // channels
#define HH 128
#define WW 128
#define SS (HH*WW)   // 16384 pixels per batch
#define NB 8         // batch
#define NK 19        // keypoints
#define STILE 64     // pixels per block

typedef __attribute__((ext_vector_type(8))) short short8v;   // 8 bf16 = 4 VGPR (MFMA operand)
typedef __attribute__((ext_vector_type(4))) float f32x4;     // MFMA accum

static __device__ __forceinline__ unsigned short f2bf(float x) {
    __hip_bfloat16 h = __float2bfloat16(x);
    return *reinterpret_cast<unsigned short*>(&h);
}
static __device__ __forceinline__ float tanh_fast(float x) {
    // 1 - 2/(e^{2x}+1): monotone, no inf-inf, exact +/-1 saturation
    float e = __expf(2.f * x);
    return 1.f - 2.f / (e + 1.f);
}

// ---------------------------------------------------------------------------
// Kernel 1: precompute folded biases, delta weights, keypoint pixels, and
// img_fc_w rearranged to bf16 in MFMA A-fragment order:
//   Wfrag[((ks*16 + ot)*64 + lane)*8 + j] = bf16(W[ot*16 + (lane&15)][ks*32 + (lane>>4)*8 + j])
// ---------------------------------------------------------------------------
__global__ __launch_bounds__(256) void precompute_kernel(
    const float* __restrict__ kf,        // [B,K,3]
    const float* __restrict__ img_fc_w,  // [256,256]
    const float* __restrict__ img_fc_b,  // [256]
    const float* __restrict__ kp_proj_w, // [19,19]
    const float* __restrict__ kp_proj_b, // [19]
    const float* __restrict__ kp_fc_w,   // [256,19]
    const float* __restrict__ kp_fc_b,   // [256]
    float* __restrict__ cb,              // [256] combined bias
    float* __restrict__ delta,           // [256*19]
    int* __restrict__ pix,               // [B*K]
    unsigned short* __restrict__ Wfrag)  // [8*16*64*8]
{
    int t = threadIdx.x;
    {
        float acc = img_fc_b[t] + kp_fc_b[t];
        for (int k2 = 0; k2 < NK; ++k2) acc += kp_fc_w[t * NK + k2] * kp_proj_b[k2];
        cb[t] = acc;
        for (int k = 0; k < NK; ++k) {
            float d = 0.f;
            for (int k2 = 0; k2 < NK; ++k2) d += kp_fc_w[t * NK + k2] * kp_proj_w[k2 * NK + k];
            delta[t * NK + k] = d;
        }
    }
    if (t < NB * NK) {
        float kx = kf[t * 3 + 0], ky = kf[t * 3 + 1], vis = kf[t * 3 + 2];
        int p = -1;
        if (vis > 0.f) {
            int xi = (int)fminf(fmaxf(kx * (1.f / (float)WW), 0.f), (float)(WW - 1));
            int yi = (int)fminf(fmaxf(ky * (1.f / (float)HH), 0.f), (float)(HH - 1));
            p = yi * WW + xi;
        }
        pix[t] = p;
    }
    for (int g = t; g < 8 * 16 * 64; g += 256) {
        int lane = g & 63;
        int ot = (g >> 6) & 15;
        int ks = g >> 10;
        int o = ot * 16 + (lane & 15);
        int c0 = ks * 32 + (lane >> 4) * 8;
#pragma unroll
        for (int j = 0; j < 8; ++j)
            Wfrag[g * 8 + j] = f2bf(img_fc_w[o * CCH + c0 + j]);
    }
}

// ---------------------------------------------------------------------------
// Kernel 2: main fused GEMM + epilogue. Block = 512 thr (8 waves), 2048 blocks.
// Tile: 256 o x 64 s. Wave w owns o in [w*32, w*32+32)  (m = 2 frags).
// Staging: thread owns 4 pixels (pq..pq+3) x 8 channels (c0..c0+7).
//   8 x float4 loads (all in flight) -> 4 x ds_write_b128 into swizzled [s][c].
//   fp32 values stay in VGPRs through the K-loop and are stored directly
//   (8 x float4 stores, scaled by score) -- no LDS readback, no reload.
// ---------------------------------------------------------------------------
__global__ __launch_bounds__(512, 4) void main_kernel(
    const float* __restrict__ img,        // [B,256,16384]
    const unsigned short* __restrict__ Wfrag,
    const float* __restrict__ cb,         // [256]
    const float* __restrict__ aw,         // attn_fc_w [256]
    const float* __restrict__ attn_b,     // [1]
    float* __restrict__ out)              // [B,256,16384]
{
    __shared__ unsigned short Xl[64 * 256];   // 32KB bf16 [s][c], 16B-block swizzled
    __shared__ float partial[8][64];
    __shared__ float scl[64];
    __shared__ float cbl[256];
    __shared__ float awl[256];

    const int t = threadIdx.x;
    const int l = t & 63;        // lane
    const int w = t >> 6;        // wave 0..7
    const int bid = blockIdx.x;
    const int b = bid >> 8;
    const int sb = (bid & 255) * STILE;
    const float* imgb = img + (size_t)b * CCH * SS;

    if (t < 256) { cbl[t] = cb[t]; awl[t] = aw[t]; }

    const int pq = (t & 15) * 4;      // pixel base this thread owns (4 px)
    const int cg = t >> 4;            // 0..31: channel group (8 ch)
    const int c0 = cg * 8;

    // ---- phase 1: 8 float4 loads (4 px x 8 ch), cvt, 4 ds_write_b128 ------
    float4 xf4[8];
#pragma unroll
    for (int j = 0; j < 8; ++j)
        xf4[j] = *reinterpret_cast<const float4*>(imgb + (size_t)(c0 + j) * SS + sb + pq);

#pragma unroll
    for (int p = 0; p < 4; ++p) {
        int s = pq + p;
        short8v pk;
#pragma unroll
        for (int j = 0; j < 8; ++j)
            pk[j] = (short)f2bf(reinterpret_cast<const float*>(&xf4[j])[p]);
        int idx = s * 256 + ((cg ^ (s & 7)) << 3);
        *reinterpret_cast<short8v*>(&Xl[idx]) = pk;
    }
    __syncthreads();

    // ---- phase 2: K loop, 8 steps of K=32, 8 MFMA per step per wave -------
    f32x4 acc[2][4];
#pragma unroll
    for (int m = 0; m < 2; ++m)
#pragma unroll
        for (int n = 0; n < 4; ++n)
            acc[m][n] = (f32x4){0.f, 0.f, 0.f, 0.f};

#pragma unroll
    for (int ks = 0; ks < 8; ++ks) {
        short8v a[2], bf[4];
#pragma unroll
        for (int m = 0; m < 2; ++m) {
            int ot = w * 2 + m;
            a[m] = *reinterpret_cast<const short8v*>(
                &Wfrag[(((ks * 16 + ot) * 64) + l) * 8]);
        }
#pragma unroll
        for (int n = 0; n < 4; ++n) {
            int s = n * 16 + (l & 15);
            int cblk = ks * 4 + (l >> 4);
            int idx = s * 256 + ((cblk ^ (s & 7)) << 3);
            bf[n] = *reinterpret_cast<const short8v*>(&Xl[idx]);
        }
#pragma unroll
        for (int m = 0; m < 2; ++m)
#pragma unroll
            for (int n = 0; n < 4; ++n)
                acc[m][n] = __builtin_amdgcn_mfma_f32_16x16x32_bf16(a[m], bf[n], acc[m][n], 0, 0, 0);
    }

    // ---- phase 3: score[s] = sigmoid(attn_b + sum_o aw[o]*tanh(T[o,s]+cb[o]))
    // D layout: col(=s within frag) = l&15, row(=o within frag) = (l>>4)*4 + r
    float p4[4];
#pragma unroll
    for (int n = 0; n < 4; ++n) {
        float accp = 0.f;
#pragma unroll
        for (int m = 0; m < 2; ++m)
#pragma unroll
            for (int r = 0; r < 4; ++r) {
                int o = (w * 2 + m) * 16 + ((l >> 4) << 2) + r;
                accp += awl[o] * tanh_fast(acc[m][n][r] + cbl[o]);
            }
        accp += __shfl_xor(accp, 16);
        accp += __shfl_xor(accp, 32);
        p4[n] = accp;
    }
    if (l < 16) {
#pragma unroll
        for (int n = 0; n < 4; ++n) partial[w][n * 16 + l] = p4[n];
    }
    __syncthreads();
    if (t < 64) {
        float z = attn_b[0];
#pragma unroll
        for (int ww = 0; ww < 8; ++ww) z += partial[ww][t];
        scl[t] = 1.f / (1.f + __expf(-z));
    }
    __syncthreads();

    // ---- phase 4: store directly from registers, scaled -------------------
    {
        float4 s4 = *reinterpret_cast<const float4*>(&scl[pq]);
#pragma unroll
        for (int j = 0; j < 8; ++j) {
            float4 v = xf4[j];
            float4 o4;
            o4.x = v.x * s4.x;
            o4.y = v.y * s4.y;
            o4.z = v.z * s4.z;
            o4.w = v.w * s4.w;
            *reinterpret_cast<float4*>(
                out + (size_t)(b * CCH + c0 + j) * SS + sb + pq) = o4;
        }
    }
}

// ---------------------------------------------------------------------------
// Kernel 3: exact fp32 fixup for keypoint pixels (<=152). One block per (b,k).
// ---------------------------------------------------------------------------
__global__ __launch_bounds__(256) void fixup_kernel(
    const float* __restrict__ img,
    const float* __restrict__ img_fc_w,
    const float* __restrict__ aw,
    const float* __restrict__ attn_b,
    const float* __restrict__ cb,
    const float* __restrict__ delta,
    const int* __restrict__ pix,
    float* __restrict__ out)
{
    int bk = blockIdx.x;            // 0..151
    int b = bk / NK;
    int p = pix[bk];
    if (p < 0) return;              // uniform branch, before any barrier
    __shared__ float x[256];
    __shared__ float red[256];
    __shared__ float ssc;
    int t = threadIdx.x;
    const float* imgb = img + (size_t)b * CCH * SS;
    x[t] = imgb[(size_t)t * SS + p];
    __syncthreads();
    float dsum = 0.f;
    for (int k2 = 0; k2 < NK; ++k2)
        if (pix[b * NK + k2] == p) dsum += delta[t * NK + k2];
    float acc = cb[t] + dsum;
    for (int c = 0; c < CCH; ++c) acc += img_fc_w[t * CCH + c] * x[c];
    red[t] = aw[t] * tanh_fast(acc);
    __syncthreads();
    for (int off = 128; off > 0; off >>= 1) {
        if (t < off) red[t] += red[t + off];
        __syncthreads();
    }
    if (t == 0) ssc = 1.f / (1.f + __expf(-(red[0] + attn_b[0])));
    __syncthreads();
    out[(size_t)(b * CCH + t) * SS + p] = x[t] * ssc;
}

// ---------------------------------------------------------------------------
extern "C" void kernel_launch(void* const* d_in, const int* in_sizes, int n_in,
                              void* d_out, int out_size, void* d_ws, size_t ws_size,
                              hipStream_t stream) {
    (void)in_sizes; (void)n_in; (void)out_size; (void)ws_size;
    const float* img       = (const float*)d_in[0];
    const float* kf        = (const float*)d_in[1];
    const float* img_fc_w  = (const float*)d_in[2];
    const float* img_fc_b  = (const float*)d_in[3];
    const float* kp_proj_w = (const float*)d_in[4];
    const float* kp_proj_b = (const float*)d_in[5];
    const float* kp_fc_w   = (const float*)d_in[6];
    const float* kp_fc_b   = (const float*)d_in[7];
    const float* attn_fc_w = (const float*)d_in[8];
    const float* attn_fc_b = (const float*)d_in[9];
    float* out = (float*)d_out;

    char* ws = (char*)d_ws;
    float* cb             = (float*)(ws);            // 256 f  ->   1024 B
    float* delta          = (float*)(ws + 1024);     // 4864 f -> 19456 B
    int*   pix            = (int*)  (ws + 20480);    // 152 i  ->   608 B
    unsigned short* Wfrag = (unsigned short*)(ws + 21504); // 65536 u16 -> 131072 B

    precompute_kernel<<<1, 256, 0, stream>>>(kf, img_fc_w, img_fc_b, kp_proj_w,
                                             kp_proj_b, kp_fc_w, kp_fc_b,
                                             cb, delta, pix, Wfrag);
    main_kernel<<<NB * (SS / STILE), 512, 0, stream>>>(img, Wfrag, cb,
                                                       attn_fc_w, attn_fc_b, out);
    fixup_kernel<<<NB * NK, 256, 0, stream>>>(img, img_fc_w, attn_fc_w, attn_fc_b,
                                              cb, delta, pix, out);
}